// Round 2
// baseline (2095.992 us; speedup 1.0000x reference)
//
#include <hip/hip_runtime.h>
#include <hip/hip_bf16.h>

// GAT layer: h = x@W ; attention dots ; edge softmax over dst (+self-loops);
// agg = sum alpha*h[src] ; bias + LayerNorm + ELU.
// N=100000, E=1600000, IN=128, HEADS=8, C=16, OUT_DIM=128.
//
// Correctness-first round: dtype-adaptive (bf16-vs-fp32 floats, int32-vs-int64
// edges) via a 1-wave detect kernel; all values sanitized so any semantic
// mismatch shows as finite absmax, never NaN. h is staged in d_out to keep
// workspace use at ~60.8 MB.

#define HEADS 8
#define CCH 16
#define DIM 128
#define KD 128
#define NEG_SLOPE 0.2f
#define LN_EPS 1e-5f

struct Flags { int fp32; int edge64; };

__device__ __forceinline__ float fin(float v) {
    return (v == v && fabsf(v) < 1e30f) ? v : 0.f;
}
__device__ __forceinline__ float loadf(const void* p, long long i, int fp32) {
    return fp32 ? ((const float*)p)[i]
                : __bfloat162float(((const __hip_bfloat16*)p)[i]);
}
__device__ __forceinline__ float lrelu(float v) { return v > 0.f ? v : NEG_SLOPE * v; }

// src/dst fetch that works for int32 or int64 (little-endian) edge_index.
__device__ __forceinline__ void get_edge(const int* ei, int e, int E, int edge64,
                                         int N, int* s, int* d) {
    int s_, d_;
    if (edge64) { s_ = ei[2LL * e]; d_ = ei[2LL * (E + e)]; }
    else        { s_ = ei[e];       d_ = ei[E + e]; }
    *s = min(max(s_, 0), N - 1);
    *d = min(max(d_, 0), N - 1);
}

// ---------------- K0: dtype detection (1 wave) ----------------
__global__ void k_detect(const unsigned int* xw, const int* ei, Flags* fl) {
    int lane = threadIdx.x;
    // fp32 test: byte1 of each word must look like bf16 sign|exp for N(0,1) data
    int viol = 0;
    for (int i = lane; i < 256; i += 64) {
        unsigned int b = (xw[i] >> 8) & 0xFF;
        unsigned int m = b & 0x7F;
        bool ok = (m >= 0x36 && m <= 0x44) || b == 0x00 || b == 0x80;
        if (!ok) viol++;
    }
    // int64 test: odd 32-bit words (high halves) all zero
    int nz = (ei[2 * lane + 1] != 0) ? 1 : 0;
#pragma unroll
    for (int off = 32; off; off >>= 1) {
        viol += __shfl_xor(viol, off);
        nz   += __shfl_xor(nz, off);
    }
    if (lane == 0) {
        fl->fp32   = (viol > 64) ? 1 : 0;
        fl->edge64 = (nz == 0) ? 1 : 0;
    }
}

// ---------------- K1: h = x@W + attention dots ----------------
// One node per wave; lane computes output channels 2l, 2l+1.
__global__ __launch_bounds__(256) void k_gemm(
    const void* __restrict__ x, const void* __restrict__ W,
    const void* __restrict__ att_s, const void* __restrict__ att_d,
    __hip_bfloat16* __restrict__ h, float* __restrict__ a_s, float* __restrict__ a_d,
    const Flags* __restrict__ fl, int N)
{
    int fp32 = fl->fp32;
    int wave = threadIdx.x >> 6, lane = threadIdx.x & 63;
    int n = blockIdx.x * 4 + wave;
    if (n >= N) return;

    long long xb = (long long)n * KD;
    int j0 = 2 * lane;
    float acc0 = 0.f, acc1 = 0.f;
    for (int k = 0; k < KD; ++k) {
        float xv = loadf(x, xb + k, fp32);
        acc0 = fmaf(xv, loadf(W, (long long)k * DIM + j0,     fp32), acc0);
        acc1 = fmaf(xv, loadf(W, (long long)k * DIM + j0 + 1, fp32), acc1);
    }
    acc0 = fin(acc0); acc1 = fin(acc1);

    __hip_bfloat162 hv;
    hv.x = __float2bfloat16(acc0);
    hv.y = __float2bfloat16(acc1);
    ((__hip_bfloat162*)h)[(long long)n * 64 + lane] = hv;

    int head = lane >> 3, c0 = j0 & 15;
    float vs = acc0 * loadf(att_s, head * CCH + c0,     fp32) +
               acc1 * loadf(att_s, head * CCH + c0 + 1, fp32);
    float vd = acc0 * loadf(att_d, head * CCH + c0,     fp32) +
               acc1 * loadf(att_d, head * CCH + c0 + 1, fp32);
    vs += __shfl_xor(vs, 4); vs += __shfl_xor(vs, 2); vs += __shfl_xor(vs, 1);
    vd += __shfl_xor(vd, 4); vd += __shfl_xor(vd, 2); vd += __shfl_xor(vd, 1);
    if ((lane & 7) == 0) {
        a_s[n * HEADS + head] = fin(vs);
        a_d[n * HEADS + head] = fin(vd);
    }
}

// ---------------- K2: softmax denominators ----------------
__global__ __launch_bounds__(256) void k_denom(
    const int* __restrict__ ei, const float* __restrict__ a_s,
    const float* __restrict__ a_d, float* __restrict__ denom,
    const Flags* __restrict__ fl, int E, int N)
{
    int edge64 = fl->edge64;
    int t = blockIdx.x * 256 + threadIdx.x;
    int TE = E + N;
    if (t >= TE * HEADS) return;
    int e = t >> 3, hh = t & 7;
    int src, dst;
    if (e < E) get_edge(ei, e, E, edge64, N, &src, &dst);
    else       src = dst = e - E;
    float ev = fin(lrelu(a_s[src * HEADS + hh] + a_d[dst * HEADS + hh]));
    atomicAdd(&denom[dst * HEADS + hh], expf(ev));
}

// ---------------- K3: weighted aggregation ----------------
__global__ __launch_bounds__(256) void k_agg(
    const int* __restrict__ ei, const float* __restrict__ a_s,
    const float* __restrict__ a_d, const float* __restrict__ denom,
    const __hip_bfloat16* __restrict__ h, float* __restrict__ agg,
    const Flags* __restrict__ fl, int E, int N)
{
    int edge64 = fl->edge64;
    long long t = (long long)blockIdx.x * 256 + threadIdx.x;
    long long tot = (long long)(E + N) * DIM;
    if (t >= tot) return;
    int e = (int)(t >> 7);
    int k = (int)(t & 127);
    int hh = k >> 4;
    int src, dst;
    if (e < E) get_edge(ei, e, E, edge64, N, &src, &dst);
    else       src = dst = e - E;
    float ev = fin(lrelu(a_s[src * HEADS + hh] + a_d[dst * HEADS + hh]));
    float dn = denom[dst * HEADS + hh];
    float alpha = (dn > 0.f) ? expf(ev) / dn : 0.f;
    float msg = alpha * __bfloat162float(h[(long long)src * DIM + k]);
    atomicAdd(&agg[(long long)dst * DIM + k], fin(msg));
}

// ---------------- K4: bias + LayerNorm + ELU ----------------
__global__ __launch_bounds__(128) void k_ln(
    const float* __restrict__ agg, const void* __restrict__ bias,
    const void* __restrict__ gamma, const void* __restrict__ beta,
    void* __restrict__ out, const Flags* __restrict__ fl, int N)
{
    int fp32 = fl->fp32;
    int n = blockIdx.x;
    int k = threadIdx.x;
    float val = fin(agg[(long long)n * DIM + k]) + loadf(bias, k, fp32);

    float s = val;
#pragma unroll
    for (int off = 32; off; off >>= 1) s += __shfl_xor(s, off);
    __shared__ float r0[2], r1[2];
    int w = k >> 6;
    if ((k & 63) == 0) r0[w] = s;
    __syncthreads();
    float mu = (r0[0] + r0[1]) * (1.0f / DIM);

    float d = val - mu;
    float q = d * d;
#pragma unroll
    for (int off = 32; off; off >>= 1) q += __shfl_xor(q, off);
    if ((k & 63) == 0) r1[w] = q;
    __syncthreads();
    float var = (r1[0] + r1[1]) * (1.0f / DIM);

    float y = d * rsqrtf(var + LN_EPS) * loadf(gamma, k, fp32) + loadf(beta, k, fp32);
    y = y > 0.f ? y : expm1f(y);  // ELU
    long long oi = (long long)n * DIM + k;
    if (fp32) ((float*)out)[oi] = y;
    else      ((__hip_bfloat16*)out)[oi] = __float2bfloat16(y);
}

extern "C" void kernel_launch(void* const* d_in, const int* in_sizes, int n_in,
                              void* d_out, int out_size, void* d_ws, size_t ws_size,
                              hipStream_t stream)
{
    const void* x    = d_in[0];
    const int*  ei   = (const int*)d_in[1];
    const void* W    = d_in[2];
    const void* atts = d_in[3];
    const void* attd = d_in[4];
    const void* bias = d_in[5];
    const void* gam  = d_in[6];
    const void* bet  = d_in[7];

    int N = in_sizes[0] / KD;   // 100000
    int E = in_sizes[1] / 2;    // 1600000 (element count /2; valid for i32 and i64)

    // workspace layout (~60.8 MB): [flags][a_s][a_d][denom][agg]
    char* p = (char*)d_ws;
    Flags* fl = (Flags*)p;    p += 16;
    float* a_s   = (float*)p; p += (size_t)N * HEADS * sizeof(float);
    float* a_d   = (float*)p; p += (size_t)N * HEADS * sizeof(float);
    float* denom = (float*)p; p += (size_t)N * HEADS * sizeof(float);
    float* agg   = (float*)p; p += (size_t)N * DIM * sizeof(float);
    // h staged in d_out (bf16, 25.6 MB) — overwritten by k_ln at the end.
    __hip_bfloat16* h = (__hip_bfloat16*)d_out;

    k_detect<<<1, 64, 0, stream>>>((const unsigned int*)x, ei, fl);

    // zero denom + agg (contiguous; ws re-poisoned before every launch)
    hipMemsetAsync(denom, 0,
                   (size_t)N * (HEADS + DIM) * sizeof(float), stream);

    k_gemm<<<(N + 3) / 4, 256, 0, stream>>>(x, W, atts, attd, h, a_s, a_d, fl, N);

    int TE = E + N;
    long long t2 = (long long)TE * HEADS;
    k_denom<<<(unsigned)((t2 + 255) / 256), 256, 0, stream>>>(ei, a_s, a_d, denom, fl, E, N);

    long long t3 = (long long)TE * DIM;
    k_agg<<<(unsigned)((t3 + 255) / 256), 256, 0, stream>>>(ei, a_s, a_d, denom, h, agg, fl, E, N);

    k_ln<<<N, DIM, 0, stream>>>(agg, bias, gam, bet, d_out, fl, N);
}

// Round 3
// 809.512 us; speedup vs baseline: 2.5892x; 2.5892x over previous
//
#include <hip/hip_runtime.h>
#include <hip/hip_bf16.h>

// GAT layer, CSR-gather formulation:
//   h = x@W ; a_s/a_d dots (k_gemm)
//   CSR build: hist -> scan -> scatter (edges grouped by dst)
//   fused per-node: unnormalized softmax gather + bias + LayerNorm + ELU
// N=100000, E=1600000, IN=128, HEADS=8, C=16, OUT_DIM=128.

#define HEADS 8
#define CCH 16
#define DIM 128
#define KD 128
#define NEG_SLOPE 0.2f
#define LN_EPS 1e-5f
#define SCAN_T 1024

struct Flags { int fp32; int edge64; };

__device__ __forceinline__ float fin(float v) {
    return (v == v && fabsf(v) < 1e30f) ? v : 0.f;
}
__device__ __forceinline__ float loadf(const void* p, long long i, int fp32) {
    return fp32 ? ((const float*)p)[i]
                : __bfloat162float(((const __hip_bfloat16*)p)[i]);
}
__device__ __forceinline__ float lrelu(float v) { return v > 0.f ? v : NEG_SLOPE * v; }

// ---------------- K0: dtype detection (1 wave) ----------------
__global__ void k_detect(const unsigned int* xw, const int* ei, Flags* fl) {
    int lane = threadIdx.x;
    int viol = 0;
    for (int i = lane; i < 256; i += 64) {
        unsigned int b = (xw[i] >> 8) & 0xFF;
        unsigned int m = b & 0x7F;
        bool ok = (m >= 0x36 && m <= 0x44) || b == 0x00 || b == 0x80;
        if (!ok) viol++;
    }
    int nz = (ei[2 * lane + 1] != 0) ? 1 : 0;
#pragma unroll
    for (int off = 32; off; off >>= 1) {
        viol += __shfl_xor(viol, off);
        nz   += __shfl_xor(nz, off);
    }
    if (lane == 0) {
        fl->fp32   = (viol > 64) ? 1 : 0;
        fl->edge64 = (nz == 0) ? 1 : 0;
    }
}

// ---------------- K1: h = x@W + attention dots ----------------
// One node per wave; lane computes output channels 2l, 2l+1. x row staged in LDS.
__global__ __launch_bounds__(256) void k_gemm(
    const void* __restrict__ x, const void* __restrict__ W,
    const void* __restrict__ att_s, const void* __restrict__ att_d,
    __hip_bfloat16* __restrict__ h, float* __restrict__ a_s, float* __restrict__ a_d,
    const Flags* __restrict__ fl, int N)
{
    int fp32 = fl->fp32;
    int wave = threadIdx.x >> 6, lane = threadIdx.x & 63;
    int n = blockIdx.x * 4 + wave;
    if (n >= N) return;

    __shared__ float xs[4][KD];
    int j0 = 2 * lane;
    if (fp32) {
        float2 v = ((const float2*)x)[(long long)n * 64 + lane];
        xs[wave][j0] = v.x; xs[wave][j0 + 1] = v.y;
    } else {
        unsigned int v = ((const unsigned int*)x)[(long long)n * 64 + lane];
        xs[wave][j0]     = __uint_as_float(v << 16);
        xs[wave][j0 + 1] = __uint_as_float(v & 0xffff0000u);
    }
    __syncthreads();

    float acc0 = 0.f, acc1 = 0.f;
    if (fp32) {
        const float2* Wp = (const float2*)W;
        for (int k = 0; k < KD; ++k) {
            float xv = xs[wave][k];
            float2 wv = Wp[(long long)k * 64 + lane];
            acc0 = fmaf(xv, wv.x, acc0);
            acc1 = fmaf(xv, wv.y, acc1);
        }
    } else {
        const unsigned int* Wp = (const unsigned int*)W;
        for (int k = 0; k < KD; ++k) {
            float xv = xs[wave][k];
            unsigned int wv = Wp[(long long)k * 64 + lane];
            acc0 = fmaf(xv, __uint_as_float(wv << 16), acc0);
            acc1 = fmaf(xv, __uint_as_float(wv & 0xffff0000u), acc1);
        }
    }
    acc0 = fin(acc0); acc1 = fin(acc1);

    __hip_bfloat162 hv;
    hv.x = __float2bfloat16(acc0);
    hv.y = __float2bfloat16(acc1);
    ((__hip_bfloat162*)h)[(long long)n * 64 + lane] = hv;

    int head = lane >> 3, c0 = j0 & 15;
    float vs = acc0 * loadf(att_s, head * CCH + c0,     fp32) +
               acc1 * loadf(att_s, head * CCH + c0 + 1, fp32);
    float vd = acc0 * loadf(att_d, head * CCH + c0,     fp32) +
               acc1 * loadf(att_d, head * CCH + c0 + 1, fp32);
    vs += __shfl_xor(vs, 4); vs += __shfl_xor(vs, 2); vs += __shfl_xor(vs, 1);
    vd += __shfl_xor(vd, 4); vd += __shfl_xor(vd, 2); vd += __shfl_xor(vd, 1);
    if ((lane & 7) == 0) {
        a_s[n * HEADS + head] = fin(vs);
        a_d[n * HEADS + head] = fin(vd);
    }
}

// ---------------- CSR build ----------------
__global__ __launch_bounds__(256) void k_hist(
    const int* __restrict__ ei, int* __restrict__ deg,
    const Flags* __restrict__ fl, int E, int N)
{
    int e = blockIdx.x * 256 + threadIdx.x;
    if (e >= E) return;
    int d = fl->edge64 ? ei[2LL * (E + e)] : ei[E + e];
    d = min(max(d, 0), N - 1);
    atomicAdd(&deg[d], 1);
}

__global__ __launch_bounds__(SCAN_T) void k_scanA(
    const int* __restrict__ deg, int* __restrict__ bsum, int N)
{
    __shared__ int sh[SCAN_T];
    int t = threadIdx.x;
    int g = blockIdx.x * SCAN_T + t;
    sh[t] = (g < N) ? deg[g] : 0;
    __syncthreads();
    for (int off = SCAN_T / 2; off; off >>= 1) {
        if (t < off) sh[t] += sh[t + off];
        __syncthreads();
    }
    if (t == 0) bsum[blockIdx.x] = sh[0];
}

__global__ void k_scanB(const int* __restrict__ bsum, int* __restrict__ boff, int nb)
{
    int acc = 0;
    for (int i = 0; i < nb; ++i) { boff[i] = acc; acc += bsum[i]; }
}

__global__ __launch_bounds__(SCAN_T) void k_scanC(
    const int* __restrict__ deg, const int* __restrict__ boff,
    int* __restrict__ row_start, int* __restrict__ cursor, int N)
{
    __shared__ int sh[SCAN_T];
    int t = threadIdx.x;
    int g = blockIdx.x * SCAN_T + t;
    int v = (g < N) ? deg[g] : 0;
    sh[t] = v;
    __syncthreads();
    for (int off = 1; off < SCAN_T; off <<= 1) {
        int u = (t >= off) ? sh[t - off] : 0;
        __syncthreads();
        sh[t] += u;
        __syncthreads();
    }
    if (g < N) {
        int excl = sh[t] - v + boff[blockIdx.x];
        row_start[g] = excl;
        cursor[g] = excl;
    }
}

__global__ __launch_bounds__(256) void k_scatter(
    const int* __restrict__ ei, int* __restrict__ cursor,
    int* __restrict__ csr_src, const Flags* __restrict__ fl, int E, int N)
{
    int e = blockIdx.x * 256 + threadIdx.x;
    if (e >= E) return;
    int s, d;
    if (fl->edge64) { s = ei[2LL * e]; d = ei[2LL * (E + e)]; }
    else            { s = ei[e];       d = ei[E + e]; }
    s = min(max(s, 0), N - 1);
    d = min(max(d, 0), N - 1);
    int pos = atomicAdd(&cursor[d], 1);
    csr_src[pos] = s;
}

// ---------------- K2: fused gather-softmax-aggregate + LN + ELU ----------------
// One node per wave. Lane l owns channels 2l,2l+1 (head = l>>3).
__global__ __launch_bounds__(256) void k_fused(
    const int* __restrict__ row_start, const int* __restrict__ deg,
    const int* __restrict__ csr_src, const float* __restrict__ a_s,
    const float* __restrict__ a_d, const __hip_bfloat16* __restrict__ h,
    const void* __restrict__ bias, const void* __restrict__ gamma,
    const void* __restrict__ beta, void* __restrict__ out,
    const Flags* __restrict__ fl, int E, int N)
{
    int fp32 = fl->fp32;
    int wave = threadIdx.x >> 6, lane = threadIdx.x & 63;
    int n = blockIdx.x * 4 + wave;
    if (n >= N) return;

    int hh = lane >> 3;
    int j0 = 2 * lane;
    const __hip_bfloat162* hp = (const __hip_bfloat162*)h;

    float adv = a_d[n * HEADS + hh];

    // self-loop
    float p = __expf(lrelu(a_s[n * HEADS + hh] + adv));
    float den = p;
    __hip_bfloat162 h2 = hp[(long long)n * 64 + lane];
    float acc0 = p * __bfloat162float(h2.x);
    float acc1 = p * __bfloat162float(h2.y);

    int start = row_start[n];
    int dg = deg[n];
    for (int base = 0; base < dg; base += 64) {
        int idx = start + base + lane;
        int my = csr_src[min(idx, E - 1)];
        int m = min(64, dg - base);
        for (int j = 0; j < m; ++j) {
            int src = __shfl(my, j);
            float pe = __expf(lrelu(a_s[src * HEADS + hh] + adv));
            den += pe;
            __hip_bfloat162 hv = hp[(long long)src * 64 + lane];
            acc0 = fmaf(pe, __bfloat162float(hv.x), acc0);
            acc1 = fmaf(pe, __bfloat162float(hv.y), acc1);
        }
    }

    float inv = 1.0f / den;
    float v0 = fin(acc0 * inv) + loadf(bias, j0,     fp32);
    float v1 = fin(acc1 * inv) + loadf(bias, j0 + 1, fp32);

    float s = v0 + v1;
#pragma unroll
    for (int off = 32; off; off >>= 1) s += __shfl_xor(s, off);
    float mu = s * (1.0f / DIM);
    float d0 = v0 - mu, d1 = v1 - mu;
    float q = d0 * d0 + d1 * d1;
#pragma unroll
    for (int off = 32; off; off >>= 1) q += __shfl_xor(q, off);
    float rs = rsqrtf(q * (1.0f / DIM) + LN_EPS);

    float y0 = d0 * rs * loadf(gamma, j0,     fp32) + loadf(beta, j0,     fp32);
    float y1 = d1 * rs * loadf(gamma, j0 + 1, fp32) + loadf(beta, j0 + 1, fp32);
    y0 = y0 > 0.f ? y0 : expm1f(y0);
    y1 = y1 > 0.f ? y1 : expm1f(y1);

    long long oi = (long long)n * 64 + lane;
    if (fp32) {
        ((float2*)out)[oi] = make_float2(y0, y1);
    } else {
        __hip_bfloat162 yv;
        yv.x = __float2bfloat16(y0);
        yv.y = __float2bfloat16(y1);
        ((__hip_bfloat162*)out)[oi] = yv;
    }
}

extern "C" void kernel_launch(void* const* d_in, const int* in_sizes, int n_in,
                              void* d_out, int out_size, void* d_ws, size_t ws_size,
                              hipStream_t stream)
{
    const void* x    = d_in[0];
    const int*  ei   = (const int*)d_in[1];
    const void* W    = d_in[2];
    const void* atts = d_in[3];
    const void* attd = d_in[4];
    const void* bias = d_in[5];
    const void* gam  = d_in[6];
    const void* bet  = d_in[7];

    int N = in_sizes[0] / KD;   // 100000
    int E = in_sizes[1] / 2;    // 1600000

    // workspace layout (~39.6 MB)
    char* p = (char*)d_ws;
    Flags* fl      = (Flags*)p; p += 1024;
    float* a_s     = (float*)p; p += (size_t)N * HEADS * sizeof(float);
    float* a_d     = (float*)p; p += (size_t)N * HEADS * sizeof(float);
    __hip_bfloat16* h = (__hip_bfloat16*)p; p += (size_t)N * DIM * sizeof(__hip_bfloat16);
    int* deg       = (int*)p;   p += (size_t)N * sizeof(int);
    int* row_start = (int*)p;   p += (size_t)N * sizeof(int);
    int* cursor    = (int*)p;   p += (size_t)N * sizeof(int);
    int* csr_src   = (int*)p;   p += (size_t)E * sizeof(int);
    int* bsum      = (int*)p;   p += 4096;
    int* boff      = (int*)p;   p += 4096;

    int nb = (N + SCAN_T - 1) / SCAN_T;

    k_detect<<<1, 64, 0, stream>>>((const unsigned int*)x, ei, fl);
    hipMemsetAsync(deg, 0, (size_t)N * sizeof(int), stream);

    k_gemm<<<(N + 3) / 4, 256, 0, stream>>>(x, W, atts, attd, h, a_s, a_d, fl, N);

    k_hist<<<(E + 255) / 256, 256, 0, stream>>>(ei, deg, fl, E, N);
    k_scanA<<<nb, SCAN_T, 0, stream>>>(deg, bsum, N);
    k_scanB<<<1, 1, 0, stream>>>(bsum, boff, nb);
    k_scanC<<<nb, SCAN_T, 0, stream>>>(deg, boff, row_start, cursor, N);
    k_scatter<<<(E + 255) / 256, 256, 0, stream>>>(ei, cursor, csr_src, fl, E, N);

    k_fused<<<(N + 3) / 4, 256, 0, stream>>>(row_start, deg, csr_src, a_s, a_d, h,
                                             bias, gam, bet, d_out, fl, E, N);
}

// Round 5
// 505.608 us; speedup vs baseline: 4.1455x; 1.6011x over previous
//
#include <hip/hip_runtime.h>
#include <hip/hip_bf16.h>

// GAT layer, CSR-gather + LDS-tiled VALU GEMM (numerics identical to R3):
//   k_gemm_lds: h = x@W, fused a_s/a_d dots. W + x-tile staged in LDS,
//               4 nodes x 8 channels per thread (32 fp32 accumulators).
//   CSR build: hist -> scan -> scatter (edges grouped by dst)
//   k_fused: per-node unnormalized softmax gather + bias + LayerNorm + ELU
// N=100000, E=1600000, IN=128, HEADS=8, C=16, OUT_DIM=128.
// Established: float inputs are bf16, output bf16 (R2/R3 evidence).

#define HEADS 8
#define CCH 16
#define DIM 128
#define KD 128
#define NEG_SLOPE 0.2f
#define LN_EPS 1e-5f
#define SCAN_T 1024
#define GN 64   // nodes per GEMM block

struct Flags { int fp32; int edge64; };

__device__ __forceinline__ float fin(float v) {
    return (v == v && fabsf(v) < 1e30f) ? v : 0.f;
}
__device__ __forceinline__ float loadf(const void* p, long long i, int fp32) {
    return fp32 ? ((const float*)p)[i]
                : __bfloat162float(((const __hip_bfloat16*)p)[i]);
}
__device__ __forceinline__ float lrelu(float v) { return v > 0.f ? v : NEG_SLOPE * v; }
__device__ __forceinline__ short f2bf_s(float v) {
    __hip_bfloat16 b = __float2bfloat16(v);
    return *reinterpret_cast<short*>(&b);
}

// ---------------- K0: dtype detection (1 wave) ----------------
__global__ void k_detect(const unsigned int* xw, const int* ei, Flags* fl) {
    int lane = threadIdx.x;
    int viol = 0;
    for (int i = lane; i < 256; i += 64) {
        unsigned int b = (xw[i] >> 8) & 0xFF;
        unsigned int m = b & 0x7F;
        bool ok = (m >= 0x36 && m <= 0x44) || b == 0x00 || b == 0x80;
        if (!ok) viol++;
    }
    int nz = (ei[2 * lane + 1] != 0) ? 1 : 0;
#pragma unroll
    for (int off = 32; off; off >>= 1) {
        viol += __shfl_xor(viol, off);
        nz   += __shfl_xor(nz, off);
    }
    if (lane == 0) {
        fl->fp32   = (viol > 64) ? 1 : 0;
        fl->edge64 = (nz == 0) ? 1 : 0;
    }
}

// ---------------- K1: h = x@W + attention dots (LDS-tiled VALU) ----------------
// Block: 256 threads, 64 nodes. Thread t: group g=t>>4 owns local nodes 4g..4g+3,
// channel slot ci=t&15 owns channels ci*8..ci*8+7. 32 fp32 accumulators.
__global__ __launch_bounds__(256, 2) void k_gemm_lds(
    const void* __restrict__ x, const void* __restrict__ W,
    const void* __restrict__ att_s, const void* __restrict__ att_d,
    __hip_bfloat16* __restrict__ h, float* __restrict__ a_s, float* __restrict__ a_d,
    const Flags* __restrict__ fl, int N)
{
    __shared__ unsigned int Wl[KD * 64];   // W row-major as bf16 pairs (32 KB)
    __shared__ float Xl[GN][132];          // x tile fp32, padded stride (33 KB)
    __shared__ float Asl[DIM], Adl[DIM];

    int fp32 = fl->fp32;
    int t = threadIdx.x;
    int n0 = blockIdx.x * GN;

    if (t < DIM) {
        Asl[t] = loadf(att_s, t, fp32);
        Adl[t] = loadf(att_d, t, fp32);
    }

    // stage W: 128x128 as 8192 u32 bf16-pairs
    if (!fp32) {
        const unsigned int* Wp = (const unsigned int*)W;
        for (int i = t; i < KD * 64; i += 256) Wl[i] = Wp[i];
    } else {
        const float* Wp = (const float*)W;
        for (int i = t; i < KD * 64; i += 256) {
            unsigned int b0 = (unsigned short)f2bf_s(Wp[2 * i]);
            unsigned int b1 = (unsigned short)f2bf_s(Wp[2 * i + 1]);
            Wl[i] = b0 | (b1 << 16);
        }
    }

    // stage x tile (64 rows x 128 ch) as fp32
    for (int i = t; i < GN * 64; i += 256) {
        int r = i >> 6, c2 = (i & 63) * 2;
        int row = min(n0 + r, N - 1);
        float v0, v1;
        if (!fp32) {
            unsigned int u = ((const unsigned int*)x)[(long long)row * 64 + (i & 63)];
            v0 = __uint_as_float(u << 16);
            v1 = __uint_as_float(u & 0xffff0000u);
        } else {
            v0 = ((const float*)x)[(long long)row * KD + c2];
            v1 = ((const float*)x)[(long long)row * KD + c2 + 1];
        }
        Xl[r][c2] = v0; Xl[r][c2 + 1] = v1;
    }
    __syncthreads();

    int g = t >> 4;
    int ci = t & 15;
    int c0 = ci * 8;

    float acc[4][8];
#pragma unroll
    for (int i = 0; i < 4; ++i)
#pragma unroll
        for (int j = 0; j < 8; ++j) acc[i][j] = 0.f;

#pragma unroll 4
    for (int k = 0; k < KD; ++k) {
        uint4 wv = *(const uint4*)&Wl[k * 64 + ci * 4];
        float w[8];
        w[0] = __uint_as_float(wv.x << 16); w[1] = __uint_as_float(wv.x & 0xffff0000u);
        w[2] = __uint_as_float(wv.y << 16); w[3] = __uint_as_float(wv.y & 0xffff0000u);
        w[4] = __uint_as_float(wv.z << 16); w[5] = __uint_as_float(wv.z & 0xffff0000u);
        w[6] = __uint_as_float(wv.w << 16); w[7] = __uint_as_float(wv.w & 0xffff0000u);
        float x0 = Xl[4 * g + 0][k];
        float x1 = Xl[4 * g + 1][k];
        float x2 = Xl[4 * g + 2][k];
        float x3 = Xl[4 * g + 3][k];
#pragma unroll
        for (int j = 0; j < 8; ++j) {
            acc[0][j] = fmaf(x0, w[j], acc[0][j]);
            acc[1][j] = fmaf(x1, w[j], acc[1][j]);
            acc[2][j] = fmaf(x2, w[j], acc[2][j]);
            acc[3][j] = fmaf(x3, w[j], acc[3][j]);
        }
    }

    // epilogue: h store (int4) + attention dots (pair-combine via shfl)
    int head = ci >> 1;
#pragma unroll
    for (int i = 0; i < 4; ++i) {
        int row = n0 + 4 * g + i;
        float vs = 0.f, vd = 0.f;
        union { __hip_bfloat162 b2[4]; int4 v; } u;
#pragma unroll
        for (int p = 0; p < 4; ++p) {
            float e0 = fin(acc[i][2 * p]), e1 = fin(acc[i][2 * p + 1]);
            vs += e0 * Asl[c0 + 2 * p] + e1 * Asl[c0 + 2 * p + 1];
            vd += e0 * Adl[c0 + 2 * p] + e1 * Adl[c0 + 2 * p + 1];
            u.b2[p].x = __float2bfloat16(e0);
            u.b2[p].y = __float2bfloat16(e1);
        }
        vs += __shfl_xor(vs, 1);
        vd += __shfl_xor(vd, 1);
        if (row < N) {
            *(int4*)(h + (long long)row * DIM + c0) = u.v;
            if ((ci & 1) == 0) {
                a_s[row * HEADS + head] = fin(vs);
                a_d[row * HEADS + head] = fin(vd);
            }
        }
    }
}

// ---------------- CSR build ----------------
__global__ __launch_bounds__(256) void k_hist(
    const int* __restrict__ ei, int* __restrict__ deg,
    const Flags* __restrict__ fl, int E, int N)
{
    int e = blockIdx.x * 256 + threadIdx.x;
    if (e >= E) return;
    int d = fl->edge64 ? ei[2LL * (E + e)] : ei[E + e];
    d = min(max(d, 0), N - 1);
    atomicAdd(&deg[d], 1);
}

__global__ __launch_bounds__(SCAN_T) void k_scanA(
    const int* __restrict__ deg, int* __restrict__ bsum, int N)
{
    __shared__ int sh[SCAN_T];
    int t = threadIdx.x;
    int g = blockIdx.x * SCAN_T + t;
    sh[t] = (g < N) ? deg[g] : 0;
    __syncthreads();
    for (int off = SCAN_T / 2; off; off >>= 1) {
        if (t < off) sh[t] += sh[t + off];
        __syncthreads();
    }
    if (t == 0) bsum[blockIdx.x] = sh[0];
}

__global__ void k_scanB(const int* __restrict__ bsum, int* __restrict__ boff, int nb)
{
    int acc = 0;
    for (int i = 0; i < nb; ++i) { boff[i] = acc; acc += bsum[i]; }
}

__global__ __launch_bounds__(SCAN_T) void k_scanC(
    const int* __restrict__ deg, const int* __restrict__ boff,
    int* __restrict__ row_start, int* __restrict__ cursor, int N)
{
    __shared__ int sh[SCAN_T];
    int t = threadIdx.x;
    int g = blockIdx.x * SCAN_T + t;
    int v = (g < N) ? deg[g] : 0;
    sh[t] = v;
    __syncthreads();
    for (int off = 1; off < SCAN_T; off <<= 1) {
        int u = (t >= off) ? sh[t - off] : 0;
        __syncthreads();
        sh[t] += u;
        __syncthreads();
    }
    if (g < N) {
        int excl = sh[t] - v + boff[blockIdx.x];
        row_start[g] = excl;
        cursor[g] = excl;
    }
}

__global__ __launch_bounds__(256) void k_scatter(
    const int* __restrict__ ei, int* __restrict__ cursor,
    int* __restrict__ csr_src, const Flags* __restrict__ fl, int E, int N)
{
    int e = blockIdx.x * 256 + threadIdx.x;
    if (e >= E) return;
    int s, d;
    if (fl->edge64) { s = ei[2LL * e]; d = ei[2LL * (E + e)]; }
    else            { s = ei[e];       d = ei[E + e]; }
    s = min(max(s, 0), N - 1);
    d = min(max(d, 0), N - 1);
    int pos = atomicAdd(&cursor[d], 1);
    csr_src[pos] = s;
}

// ---------------- K2: fused gather-softmax-aggregate + LN + ELU ----------------
// One node per wave. Lane l owns channels 2l,2l+1 (head = l>>3).
__global__ __launch_bounds__(256) void k_fused(
    const int* __restrict__ row_start, const int* __restrict__ deg,
    const int* __restrict__ csr_src, const float* __restrict__ a_s,
    const float* __restrict__ a_d, const __hip_bfloat16* __restrict__ h,
    const void* __restrict__ bias, const void* __restrict__ gamma,
    const void* __restrict__ beta, void* __restrict__ out,
    const Flags* __restrict__ fl, int E, int N)
{
    int fp32 = fl->fp32;
    int wave = threadIdx.x >> 6, lane = threadIdx.x & 63;
    int n = blockIdx.x * 4 + wave;
    if (n >= N) return;

    int hh = lane >> 3;
    int j0 = 2 * lane;
    const __hip_bfloat162* hp = (const __hip_bfloat162*)h;

    float adv = a_d[n * HEADS + hh];

    // self-loop
    float p = __expf(lrelu(a_s[n * HEADS + hh] + adv));
    float den = p;
    __hip_bfloat162 h2 = hp[(long long)n * 64 + lane];
    float acc0 = p * __bfloat162float(h2.x);
    float acc1 = p * __bfloat162float(h2.y);

    int start = row_start[n];
    int dg = deg[n];
    for (int base = 0; base < dg; base += 64) {
        int idx = start + base + lane;
        int my = csr_src[min(idx, E - 1)];
        int m = min(64, dg - base);
        for (int j = 0; j < m; ++j) {
            int src = __shfl(my, j);
            float pe = __expf(lrelu(a_s[src * HEADS + hh] + adv));
            den += pe;
            __hip_bfloat162 hv = hp[(long long)src * 64 + lane];
            acc0 = fmaf(pe, __bfloat162float(hv.x), acc0);
            acc1 = fmaf(pe, __bfloat162float(hv.y), acc1);
        }
    }

    float inv = 1.0f / den;
    float v0 = fin(acc0 * inv) + loadf(bias, j0,     fp32);
    float v1 = fin(acc1 * inv) + loadf(bias, j0 + 1, fp32);

    float s = v0 + v1;
#pragma unroll
    for (int off = 32; off; off >>= 1) s += __shfl_xor(s, off);
    float mu = s * (1.0f / DIM);
    float d0 = v0 - mu, d1 = v1 - mu;
    float q = d0 * d0 + d1 * d1;
#pragma unroll
    for (int off = 32; off; off >>= 1) q += __shfl_xor(q, off);
    float rs = rsqrtf(q * (1.0f / DIM) + LN_EPS);

    float y0 = d0 * rs * loadf(gamma, j0,     fp32) + loadf(beta, j0,     fp32);
    float y1 = d1 * rs * loadf(gamma, j0 + 1, fp32) + loadf(beta, j0 + 1, fp32);
    y0 = y0 > 0.f ? y0 : expm1f(y0);
    y1 = y1 > 0.f ? y1 : expm1f(y1);

    long long oi = (long long)n * 64 + lane;
    if (fp32) {
        ((float2*)out)[oi] = make_float2(y0, y1);
    } else {
        __hip_bfloat162 yv;
        yv.x = __float2bfloat16(y0);
        yv.y = __float2bfloat16(y1);
        ((__hip_bfloat162*)out)[oi] = yv;
    }
}

extern "C" void kernel_launch(void* const* d_in, const int* in_sizes, int n_in,
                              void* d_out, int out_size, void* d_ws, size_t ws_size,
                              hipStream_t stream)
{
    const void* x    = d_in[0];
    const int*  ei   = (const int*)d_in[1];
    const void* W    = d_in[2];
    const void* atts = d_in[3];
    const void* attd = d_in[4];
    const void* bias = d_in[5];
    const void* gam  = d_in[6];
    const void* bet  = d_in[7];

    int N = in_sizes[0] / KD;   // 100000
    int E = in_sizes[1] / 2;    // 1600000

    // workspace layout (~39.6 MB, same as proven R3)
    char* p = (char*)d_ws;
    Flags* fl      = (Flags*)p; p += 1024;
    float* a_s     = (float*)p; p += (size_t)N * HEADS * sizeof(float);
    float* a_d     = (float*)p; p += (size_t)N * HEADS * sizeof(float);
    __hip_bfloat16* h = (__hip_bfloat16*)p; p += (size_t)N * DIM * sizeof(__hip_bfloat16);
    int* deg       = (int*)p;   p += (size_t)N * sizeof(int);
    int* row_start = (int*)p;   p += (size_t)N * sizeof(int);
    int* cursor    = (int*)p;   p += (size_t)N * sizeof(int);
    int* csr_src   = (int*)p;   p += (size_t)E * sizeof(int);
    int* bsum      = (int*)p;   p += 4096;
    int* boff      = (int*)p;   p += 4096;

    int nb = (N + SCAN_T - 1) / SCAN_T;

    k_detect<<<1, 64, 0, stream>>>((const unsigned int*)x, ei, fl);
    hipMemsetAsync(deg, 0, (size_t)N * sizeof(int), stream);

    k_gemm_lds<<<(N + GN - 1) / GN, 256, 0, stream>>>(x, W, atts, attd, h, a_s, a_d, fl, N);

    k_hist<<<(E + 255) / 256, 256, 0, stream>>>(ei, deg, fl, E, N);
    k_scanA<<<nb, SCAN_T, 0, stream>>>(deg, bsum, N);
    k_scanB<<<1, 1, 0, stream>>>(bsum, boff, nb);
    k_scanC<<<nb, SCAN_T, 0, stream>>>(deg, boff, row_start, cursor, N);
    k_scatter<<<(E + 255) / 256, 256, 0, stream>>>(ei, cursor, csr_src, fl, E, N);

    k_fused<<<(N + 3) / 4, 256, 0, stream>>>(row_start, deg, csr_src, a_s, a_d, h,
                                             bias, gam, bet, d_out, fl, E, N);
}

// Round 6
// 472.205 us; speedup vs baseline: 4.4387x; 1.0707x over previous
//
#include <hip/hip_runtime.h>
#include <hip/hip_bf16.h>

// GAT layer, CSR-gather + LDS-tiled VALU GEMM.
//   k_gemm_lds: h = x@W, fused a_s/a_d dots (proven R5).
//   CSR build: hist -> k_alloc (unordered segment allocation, no scan) -> scatter
//   k_fused: per-node unnormalized softmax gather (readlane + saddr loads,
//            4x unrolled) + bias + LayerNorm + ELU
// N=100000, E=1600000, IN=128, HEADS=8, C=16, OUT_DIM=128.
// Established: float inputs are bf16, output bf16 (R2/R3 evidence).

#define HEADS 8
#define CCH 16
#define DIM 128
#define KD 128
#define NEG_SLOPE 0.2f
#define LN_EPS 1e-5f
#define GN 64   // nodes per GEMM block

struct Flags { int fp32; int edge64; };

__device__ __forceinline__ float fin(float v) {
    return (v == v && fabsf(v) < 1e30f) ? v : 0.f;
}
__device__ __forceinline__ float loadf(const void* p, long long i, int fp32) {
    return fp32 ? ((const float*)p)[i]
                : __bfloat162float(((const __hip_bfloat16*)p)[i]);
}
__device__ __forceinline__ float lrelu(float v) { return v > 0.f ? v : NEG_SLOPE * v; }
__device__ __forceinline__ short f2bf_s(float v) {
    __hip_bfloat16 b = __float2bfloat16(v);
    return *reinterpret_cast<short*>(&b);
}
__device__ __forceinline__ float bflo(unsigned int u) { return __uint_as_float(u << 16); }
__device__ __forceinline__ float bfhi(unsigned int u) { return __uint_as_float(u & 0xffff0000u); }

// ---------------- K0: dtype detection (1 wave) ----------------
__global__ void k_detect(const unsigned int* xw, const int* ei, Flags* fl) {
    int lane = threadIdx.x;
    int viol = 0;
    for (int i = lane; i < 256; i += 64) {
        unsigned int b = (xw[i] >> 8) & 0xFF;
        unsigned int m = b & 0x7F;
        bool ok = (m >= 0x36 && m <= 0x44) || b == 0x00 || b == 0x80;
        if (!ok) viol++;
    }
    int nz = (ei[2 * lane + 1] != 0) ? 1 : 0;
#pragma unroll
    for (int off = 32; off; off >>= 1) {
        viol += __shfl_xor(viol, off);
        nz   += __shfl_xor(nz, off);
    }
    if (lane == 0) {
        fl->fp32   = (viol > 64) ? 1 : 0;
        fl->edge64 = (nz == 0) ? 1 : 0;
    }
}

// ---------------- K1: h = x@W + attention dots (LDS-tiled VALU) ----------------
__global__ __launch_bounds__(256, 2) void k_gemm_lds(
    const void* __restrict__ x, const void* __restrict__ W,
    const void* __restrict__ att_s, const void* __restrict__ att_d,
    __hip_bfloat16* __restrict__ h, float* __restrict__ a_s, float* __restrict__ a_d,
    const Flags* __restrict__ fl, int N)
{
    __shared__ unsigned int Wl[KD * 64];   // W row-major as bf16 pairs (32 KB)
    __shared__ float Xl[GN][132];          // x tile fp32, padded stride (33 KB)
    __shared__ float Asl[DIM], Adl[DIM];

    int fp32 = fl->fp32;
    int t = threadIdx.x;
    int n0 = blockIdx.x * GN;

    if (t < DIM) {
        Asl[t] = loadf(att_s, t, fp32);
        Adl[t] = loadf(att_d, t, fp32);
    }

    if (!fp32) {
        const unsigned int* Wp = (const unsigned int*)W;
        for (int i = t; i < KD * 64; i += 256) Wl[i] = Wp[i];
    } else {
        const float* Wp = (const float*)W;
        for (int i = t; i < KD * 64; i += 256) {
            unsigned int b0 = (unsigned short)f2bf_s(Wp[2 * i]);
            unsigned int b1 = (unsigned short)f2bf_s(Wp[2 * i + 1]);
            Wl[i] = b0 | (b1 << 16);
        }
    }

    for (int i = t; i < GN * 64; i += 256) {
        int r = i >> 6, c2 = (i & 63) * 2;
        int row = min(n0 + r, N - 1);
        float v0, v1;
        if (!fp32) {
            unsigned int u = ((const unsigned int*)x)[(long long)row * 64 + (i & 63)];
            v0 = bflo(u); v1 = bfhi(u);
        } else {
            v0 = ((const float*)x)[(long long)row * KD + c2];
            v1 = ((const float*)x)[(long long)row * KD + c2 + 1];
        }
        Xl[r][c2] = v0; Xl[r][c2 + 1] = v1;
    }
    __syncthreads();

    int g = t >> 4;
    int ci = t & 15;
    int c0 = ci * 8;

    float acc[4][8];
#pragma unroll
    for (int i = 0; i < 4; ++i)
#pragma unroll
        for (int j = 0; j < 8; ++j) acc[i][j] = 0.f;

#pragma unroll 4
    for (int k = 0; k < KD; ++k) {
        uint4 wv = *(const uint4*)&Wl[k * 64 + ci * 4];
        float w[8];
        w[0] = bflo(wv.x); w[1] = bfhi(wv.x);
        w[2] = bflo(wv.y); w[3] = bfhi(wv.y);
        w[4] = bflo(wv.z); w[5] = bfhi(wv.z);
        w[6] = bflo(wv.w); w[7] = bfhi(wv.w);
        float x0 = Xl[4 * g + 0][k];
        float x1 = Xl[4 * g + 1][k];
        float x2 = Xl[4 * g + 2][k];
        float x3 = Xl[4 * g + 3][k];
#pragma unroll
        for (int j = 0; j < 8; ++j) {
            acc[0][j] = fmaf(x0, w[j], acc[0][j]);
            acc[1][j] = fmaf(x1, w[j], acc[1][j]);
            acc[2][j] = fmaf(x2, w[j], acc[2][j]);
            acc[3][j] = fmaf(x3, w[j], acc[3][j]);
        }
    }

    int head = ci >> 1;
#pragma unroll
    for (int i = 0; i < 4; ++i) {
        int row = n0 + 4 * g + i;
        float vs = 0.f, vd = 0.f;
        union { __hip_bfloat162 b2[4]; int4 v; } u;
#pragma unroll
        for (int p = 0; p < 4; ++p) {
            float e0 = fin(acc[i][2 * p]), e1 = fin(acc[i][2 * p + 1]);
            vs += e0 * Asl[c0 + 2 * p] + e1 * Asl[c0 + 2 * p + 1];
            vd += e0 * Adl[c0 + 2 * p] + e1 * Adl[c0 + 2 * p + 1];
            u.b2[p].x = __float2bfloat16(e0);
            u.b2[p].y = __float2bfloat16(e1);
        }
        vs += __shfl_xor(vs, 1);
        vd += __shfl_xor(vd, 1);
        if (row < N) {
            *(int4*)(h + (long long)row * DIM + c0) = u.v;
            if ((ci & 1) == 0) {
                a_s[row * HEADS + head] = fin(vs);
                a_d[row * HEADS + head] = fin(vd);
            }
        }
    }
}

// ---------------- CSR build ----------------
__global__ __launch_bounds__(256) void k_hist(
    const int* __restrict__ ei, int* __restrict__ deg,
    const Flags* __restrict__ fl, int E, int N)
{
    int e = blockIdx.x * 256 + threadIdx.x;
    if (e >= E) return;
    int d = fl->edge64 ? ei[2LL * (E + e)] : ei[E + e];
    d = min(max(d, 0), N - 1);
    atomicAdd(&deg[d], 1);
}

// Unordered segment allocation: wave prefix-sum + one atomic per wave.
__global__ __launch_bounds__(256) void k_alloc(
    const int* __restrict__ deg, int* __restrict__ row_start,
    int* __restrict__ cursor, int* __restrict__ total, int N)
{
    int n = blockIdx.x * 256 + threadIdx.x;
    int lane = threadIdx.x & 63;
    int v = (n < N) ? deg[n] : 0;
    int val = v;
#pragma unroll
    for (int off = 1; off < 64; off <<= 1) {
        int u = __shfl_up(val, off);
        if (lane >= off) val += u;
    }
    int basev = 0;
    if (lane == 63) basev = atomicAdd(total, val);   // val@63 = wave sum
    basev = __shfl(basev, 63);
    if (n < N) {
        int rs = basev + val - v;   // exclusive prefix
        row_start[n] = rs;
        cursor[n] = rs;
    }
}

__global__ __launch_bounds__(256) void k_scatter(
    const int* __restrict__ ei, int* __restrict__ cursor,
    int* __restrict__ csr_src, const Flags* __restrict__ fl, int E, int N)
{
    int e = blockIdx.x * 256 + threadIdx.x;
    if (e >= E) return;
    int s, d;
    if (fl->edge64) { s = ei[2LL * e]; d = ei[2LL * (E + e)]; }
    else            { s = ei[e];       d = ei[E + e]; }
    s = min(max(s, 0), N - 1);
    d = min(max(d, 0), N - 1);
    int pos = atomicAdd(&cursor[d], 1);
    csr_src[pos] = s;
}

// ---------------- K2: fused gather-softmax-aggregate + LN + ELU ----------------
// One node per wave. Lane l owns channels 2l,2l+1 (head = l>>3).
// Inner loop: readlane-scalarized src + saddr h loads, 4x unrolled.
__global__ __launch_bounds__(256) void k_fused(
    const int* __restrict__ row_start, const int* __restrict__ deg,
    const int* __restrict__ csr_src, const float* __restrict__ a_s,
    const float* __restrict__ a_d, const __hip_bfloat16* __restrict__ h,
    const void* __restrict__ bias, const void* __restrict__ gamma,
    const void* __restrict__ beta, void* __restrict__ out,
    const Flags* __restrict__ fl, int E, int N)
{
    int fp32 = fl->fp32;
    int wave = threadIdx.x >> 6, lane = threadIdx.x & 63;
    int n = blockIdx.x * 4 + wave;
    if (n >= N) return;

    int hh = lane >> 3;
    int j0 = 2 * lane;
    const unsigned int* hw = (const unsigned int*)h;   // bf16 pair per uint

    // hoisted epilogue params (overlap with gather latency)
    float bi0 = loadf(bias, j0, fp32),  bi1 = loadf(bias, j0 + 1, fp32);
    float ga0 = loadf(gamma, j0, fp32), ga1 = loadf(gamma, j0 + 1, fp32);
    float be0 = loadf(beta, j0, fp32),  be1 = loadf(beta, j0 + 1, fp32);

    float adv = a_d[n * HEADS + hh];

    // self-loop
    float p = __expf(lrelu(a_s[n * HEADS + hh] + adv));
    float den = p;
    unsigned int hu = hw[(long long)n * 64 + lane];
    float acc0 = p * bflo(hu);
    float acc1 = p * bfhi(hu);

    int start = __builtin_amdgcn_readfirstlane(row_start[n]);
    int dg    = __builtin_amdgcn_readfirstlane(deg[n]);

    for (int base = 0; base < dg; base += 64) {
        int idx = start + base + lane;
        int my = csr_src[min(idx, E - 1)];
        int m = min(64, dg - base);
        int j = 0;
        for (; j + 4 <= m; j += 4) {
            int s0 = __builtin_amdgcn_readlane(my, j);
            int s1 = __builtin_amdgcn_readlane(my, j + 1);
            int s2 = __builtin_amdgcn_readlane(my, j + 2);
            int s3 = __builtin_amdgcn_readlane(my, j + 3);
            unsigned int u0 = hw[((long long)s0 << 6) + lane];
            unsigned int u1 = hw[((long long)s1 << 6) + lane];
            unsigned int u2 = hw[((long long)s2 << 6) + lane];
            unsigned int u3 = hw[((long long)s3 << 6) + lane];
            float as0 = a_s[s0 * HEADS + hh];
            float as1 = a_s[s1 * HEADS + hh];
            float as2 = a_s[s2 * HEADS + hh];
            float as3 = a_s[s3 * HEADS + hh];
            float p0 = __expf(lrelu(as0 + adv));
            float p1 = __expf(lrelu(as1 + adv));
            float p2 = __expf(lrelu(as2 + adv));
            float p3 = __expf(lrelu(as3 + adv));
            den += p0 + p1 + p2 + p3;
            acc0 = fmaf(p0, bflo(u0), acc0); acc1 = fmaf(p0, bfhi(u0), acc1);
            acc0 = fmaf(p1, bflo(u1), acc0); acc1 = fmaf(p1, bfhi(u1), acc1);
            acc0 = fmaf(p2, bflo(u2), acc0); acc1 = fmaf(p2, bfhi(u2), acc1);
            acc0 = fmaf(p3, bflo(u3), acc0); acc1 = fmaf(p3, bfhi(u3), acc1);
        }
        for (; j < m; ++j) {
            int s0 = __builtin_amdgcn_readlane(my, j);
            unsigned int u0 = hw[((long long)s0 << 6) + lane];
            float p0 = __expf(lrelu(a_s[s0 * HEADS + hh] + adv));
            den += p0;
            acc0 = fmaf(p0, bflo(u0), acc0);
            acc1 = fmaf(p0, bfhi(u0), acc1);
        }
    }

    float inv = 1.0f / den;
    float v0 = fin(acc0 * inv) + bi0;
    float v1 = fin(acc1 * inv) + bi1;

    float s = v0 + v1;
#pragma unroll
    for (int off = 32; off; off >>= 1) s += __shfl_xor(s, off);
    float mu = s * (1.0f / DIM);
    float d0 = v0 - mu, d1 = v1 - mu;
    float q = d0 * d0 + d1 * d1;
#pragma unroll
    for (int off = 32; off; off >>= 1) q += __shfl_xor(q, off);
    float rs = rsqrtf(q * (1.0f / DIM) + LN_EPS);

    float y0 = d0 * rs * ga0 + be0;
    float y1 = d1 * rs * ga1 + be1;
    y0 = y0 > 0.f ? y0 : expm1f(y0);
    y1 = y1 > 0.f ? y1 : expm1f(y1);

    long long oi = (long long)n * 64 + lane;
    if (fp32) {
        ((float2*)out)[oi] = make_float2(y0, y1);
    } else {
        __hip_bfloat162 yv;
        yv.x = __float2bfloat16(y0);
        yv.y = __float2bfloat16(y1);
        ((__hip_bfloat162*)out)[oi] = yv;
    }
}

extern "C" void kernel_launch(void* const* d_in, const int* in_sizes, int n_in,
                              void* d_out, int out_size, void* d_ws, size_t ws_size,
                              hipStream_t stream)
{
    const void* x    = d_in[0];
    const int*  ei   = (const int*)d_in[1];
    const void* W    = d_in[2];
    const void* atts = d_in[3];
    const void* attd = d_in[4];
    const void* bias = d_in[5];
    const void* gam  = d_in[6];
    const void* bet  = d_in[7];

    int N = in_sizes[0] / KD;   // 100000
    int E = in_sizes[1] / 2;    // 1600000

    // workspace layout (~36 MB)
    char* p = (char*)d_ws;
    Flags* fl      = (Flags*)p; p += 1024;
    float* a_s     = (float*)p; p += (size_t)N * HEADS * sizeof(float);
    float* a_d     = (float*)p; p += (size_t)N * HEADS * sizeof(float);
    __hip_bfloat16* h = (__hip_bfloat16*)p; p += (size_t)N * DIM * sizeof(__hip_bfloat16);
    int* deg       = (int*)p;   p += (size_t)N * sizeof(int);
    int* total     = (int*)p;   p += 64;           // adjacent to deg: one memset
    int* row_start = (int*)p;   p += (size_t)N * sizeof(int);
    int* cursor    = (int*)p;   p += (size_t)N * sizeof(int);
    int* csr_src   = (int*)p;   p += (size_t)E * sizeof(int);

    k_detect<<<1, 64, 0, stream>>>((const unsigned int*)x, ei, fl);
    hipMemsetAsync(deg, 0, (size_t)N * sizeof(int) + 64, stream);

    k_gemm_lds<<<(N + GN - 1) / GN, 256, 0, stream>>>(x, W, atts, attd, h, a_s, a_d, fl, N);

    k_hist<<<(E + 255) / 256, 256, 0, stream>>>(ei, deg, fl, E, N);
    k_alloc<<<(N + 255) / 256, 256, 0, stream>>>(deg, row_start, cursor, total, N);
    k_scatter<<<(E + 255) / 256, 256, 0, stream>>>(ei, cursor, csr_src, fl, E, N);

    k_fused<<<(N + 3) / 4, 256, 0, stream>>>(row_start, deg, csr_src, a_s, a_d, h,
                                             bias, gam, bet, d_out, fl, E, N);
}

// Round 7
// 393.658 us; speedup vs baseline: 5.3244x; 1.1995x over previous
//
#include <hip/hip_runtime.h>
#include <hip/hip_bf16.h>

// GAT layer: LDS-tiled VALU GEMM + stripe-bucketed edge binning + fused gather.
//   k_gemm_lds: h = x@W, fused a_s/a_d dots (proven R5/R6).
//   k_bhist/k_bscan/k_bscatter: edges binned by (bucket = dst>>7, stripe =
//     (e>>8)&7). Stripe == scatter-block's blockIdx&7 -> one XCD per region
//     (heuristic, perf-only): appends fill L2 lines before eviction.
//   k_fused_b: one block per bucket (128 nodes); re-bins edges into per-node
//     LDS src lists, then per-node softmax-gather + bias + LayerNorm + ELU.
// N=100000, E=1600000, IN=128, HEADS=8, C=16, OUT_DIM=128.
// Established: float inputs bf16, output bf16 (R2/R3 evidence).

#define HEADS 8
#define DIM 128
#define KD 128
#define NEG_SLOPE 0.2f
#define LN_EPS 1e-5f
#define GN 64        // nodes per GEMM block
#define BSH 7        // bucket shift: 128 nodes per bucket
#define BCAP 4096    // LDS edge capacity per bucket (mean 2048, sigma 45)

struct Flags { int fp32; int edge64; };

__device__ __forceinline__ float fin(float v) {
    return (v == v && fabsf(v) < 1e30f) ? v : 0.f;
}
__device__ __forceinline__ float loadf(const void* p, long long i, int fp32) {
    return fp32 ? ((const float*)p)[i]
                : __bfloat162float(((const __hip_bfloat16*)p)[i]);
}
__device__ __forceinline__ float lrelu(float v) { return v > 0.f ? v : NEG_SLOPE * v; }
__device__ __forceinline__ short f2bf_s(float v) {
    __hip_bfloat16 b = __float2bfloat16(v);
    return *reinterpret_cast<short*>(&b);
}
__device__ __forceinline__ float bflo(unsigned int u) { return __uint_as_float(u << 16); }
__device__ __forceinline__ float bfhi(unsigned int u) { return __uint_as_float(u & 0xffff0000u); }

// ---------------- K0: dtype detection (1 wave) ----------------
__global__ void k_detect(const unsigned int* xw, const int* ei, Flags* fl) {
    int lane = threadIdx.x;
    int viol = 0;
    for (int i = lane; i < 256; i += 64) {
        unsigned int b = (xw[i] >> 8) & 0xFF;
        unsigned int m = b & 0x7F;
        bool ok = (m >= 0x36 && m <= 0x44) || b == 0x00 || b == 0x80;
        if (!ok) viol++;
    }
    int nz = (ei[2 * lane + 1] != 0) ? 1 : 0;
#pragma unroll
    for (int off = 32; off; off >>= 1) {
        viol += __shfl_xor(viol, off);
        nz   += __shfl_xor(nz, off);
    }
    if (lane == 0) {
        fl->fp32   = (viol > 64) ? 1 : 0;
        fl->edge64 = (nz == 0) ? 1 : 0;
    }
}

// ---------------- K1: h = x@W + attention dots (LDS-tiled VALU) ----------------
__global__ __launch_bounds__(256, 2) void k_gemm_lds(
    const void* __restrict__ x, const void* __restrict__ W,
    const void* __restrict__ att_s, const void* __restrict__ att_d,
    __hip_bfloat16* __restrict__ h, float* __restrict__ a_s, float* __restrict__ a_d,
    const Flags* __restrict__ fl, int N)
{
    __shared__ unsigned int Wl[KD * 64];   // W row-major as bf16 pairs (32 KB)
    __shared__ float Xl[GN][132];          // x tile fp32, padded stride (33 KB)
    __shared__ float Asl[DIM], Adl[DIM];

    int fp32 = fl->fp32;
    int t = threadIdx.x;
    int n0 = blockIdx.x * GN;

    if (t < DIM) {
        Asl[t] = loadf(att_s, t, fp32);
        Adl[t] = loadf(att_d, t, fp32);
    }

    if (!fp32) {
        const unsigned int* Wp = (const unsigned int*)W;
        for (int i = t; i < KD * 64; i += 256) Wl[i] = Wp[i];
    } else {
        const float* Wp = (const float*)W;
        for (int i = t; i < KD * 64; i += 256) {
            unsigned int b0 = (unsigned short)f2bf_s(Wp[2 * i]);
            unsigned int b1 = (unsigned short)f2bf_s(Wp[2 * i + 1]);
            Wl[i] = b0 | (b1 << 16);
        }
    }

    for (int i = t; i < GN * 64; i += 256) {
        int r = i >> 6, c2 = (i & 63) * 2;
        int row = min(n0 + r, N - 1);
        float v0, v1;
        if (!fp32) {
            unsigned int u = ((const unsigned int*)x)[(long long)row * 64 + (i & 63)];
            v0 = bflo(u); v1 = bfhi(u);
        } else {
            v0 = ((const float*)x)[(long long)row * KD + c2];
            v1 = ((const float*)x)[(long long)row * KD + c2 + 1];
        }
        Xl[r][c2] = v0; Xl[r][c2 + 1] = v1;
    }
    __syncthreads();

    int g = t >> 4;
    int ci = t & 15;
    int c0 = ci * 8;

    float acc[4][8];
#pragma unroll
    for (int i = 0; i < 4; ++i)
#pragma unroll
        for (int j = 0; j < 8; ++j) acc[i][j] = 0.f;

#pragma unroll 4
    for (int k = 0; k < KD; ++k) {
        uint4 wv = *(const uint4*)&Wl[k * 64 + ci * 4];
        float w[8];
        w[0] = bflo(wv.x); w[1] = bfhi(wv.x);
        w[2] = bflo(wv.y); w[3] = bfhi(wv.y);
        w[4] = bflo(wv.z); w[5] = bfhi(wv.z);
        w[6] = bflo(wv.w); w[7] = bfhi(wv.w);
        float x0 = Xl[4 * g + 0][k];
        float x1 = Xl[4 * g + 1][k];
        float x2 = Xl[4 * g + 2][k];
        float x3 = Xl[4 * g + 3][k];
#pragma unroll
        for (int j = 0; j < 8; ++j) {
            acc[0][j] = fmaf(x0, w[j], acc[0][j]);
            acc[1][j] = fmaf(x1, w[j], acc[1][j]);
            acc[2][j] = fmaf(x2, w[j], acc[2][j]);
            acc[3][j] = fmaf(x3, w[j], acc[3][j]);
        }
    }

    int head = ci >> 1;
#pragma unroll
    for (int i = 0; i < 4; ++i) {
        int row = n0 + 4 * g + i;
        float vs = 0.f, vd = 0.f;
        union { __hip_bfloat162 b2[4]; int4 v; } u;
#pragma unroll
        for (int p = 0; p < 4; ++p) {
            float e0 = fin(acc[i][2 * p]), e1 = fin(acc[i][2 * p + 1]);
            vs += e0 * Asl[c0 + 2 * p] + e1 * Asl[c0 + 2 * p + 1];
            vd += e0 * Adl[c0 + 2 * p] + e1 * Adl[c0 + 2 * p + 1];
            u.b2[p].x = __float2bfloat16(e0);
            u.b2[p].y = __float2bfloat16(e1);
        }
        vs += __shfl_xor(vs, 1);
        vd += __shfl_xor(vd, 1);
        if (row < N) {
            *(int4*)(h + (long long)row * DIM + c0) = u.v;
            if ((ci & 1) == 0) {
                a_s[row * HEADS + head] = fin(vs);
                a_d[row * HEADS + head] = fin(vd);
            }
        }
    }
}

// ---------------- K2: per-(bucket,stripe) histogram ----------------
// stripe(e) = (e>>8)&7 == blockIdx&7 of the 256-thread scatter block (XCD id
// heuristic). Block (s=blockIdx&7, j=blockIdx>>3) covers chunks c==s (mod 8).
__global__ __launch_bounds__(256) void k_bhist(
    const int* __restrict__ ei, int* __restrict__ gcnt,
    const Flags* __restrict__ fl, int E, int N)
{
    __shared__ int lh[1024];
    int t = threadIdx.x;
    int s = blockIdx.x & 7, j = blockIdx.x >> 3;
    for (int i = t; i < 1024; i += 256) lh[i] = 0;
    __syncthreads();
    int edge64 = fl->edge64;
    for (long long c = s + 8LL * j; c * 256 < E; c += 8 * 32) {
        long long e = c * 256 + t;
        if (e < E) {
            int d = edge64 ? ei[2 * (E + e)] : ei[E + e];
            d = min(max(d, 0), N - 1);
            atomicAdd(&lh[d >> BSH], 1);
        }
    }
    __syncthreads();
    for (int i = t; i < 1024; i += 256)
        if (lh[i]) atomicAdd(&gcnt[s * 1024 + i], lh[i]);
}

// ---------------- K3: scan 8x1024 counts -> region bases + cursors ----------------
__global__ __launch_bounds__(1024) void k_bscan(
    const int* __restrict__ gcnt, int* __restrict__ base8, int* __restrict__ gcur)
{
    __shared__ int sh[1024];
    int t = threadIdx.x;
    int loc[8], sum = 0;
#pragma unroll
    for (int j = 0; j < 8; ++j) { loc[j] = sum; sum += gcnt[t * 8 + j]; }
    sh[t] = sum;
    __syncthreads();
    for (int off = 1; off < 1024; off <<= 1) {
        int u = (t >= off) ? sh[t - off] : 0;
        __syncthreads();
        sh[t] += u;
        __syncthreads();
    }
    int excl = sh[t] - sum;
#pragma unroll
    for (int j = 0; j < 8; ++j) {
        base8[t * 8 + j] = excl + loc[j];
        gcur[t * 8 + j]  = excl + loc[j];
    }
}

// ---------------- K4: scatter packed edges into (bucket,stripe) regions ----------------
__global__ __launch_bounds__(256) void k_bscatter(
    const int* __restrict__ ei, int* __restrict__ gcur,
    unsigned int* __restrict__ ebuf, const Flags* __restrict__ fl, int E, int N)
{
    int s = blockIdx.x & 7;
    long long e = blockIdx.x * 256LL + threadIdx.x;
    if (e >= E) return;
    int src, dst;
    if (fl->edge64) { src = ei[2 * e]; dst = ei[2 * (E + e)]; }
    else            { src = ei[e];     dst = ei[E + e]; }
    src = min(max(src, 0), N - 1);
    dst = min(max(dst, 0), N - 1);
    int bkt = dst >> BSH;
    unsigned int u = (unsigned int)src | ((unsigned int)(dst & 127) << 17);
    int pos = atomicAdd(&gcur[s * 1024 + bkt], 1);
    ebuf[pos] = u;
}

// ---------------- K5: per-bucket fused gather-softmax + bias + LN + ELU ----------------
// One block per bucket (128 nodes). Re-bin edges into per-node LDS src lists
// (two-pass: count, scan, scatter), then 8 waves x 16 nodes gather.
__global__ __launch_bounds__(512) void k_fused_b(
    const int* __restrict__ gcnt, const int* __restrict__ base8,
    const unsigned int* __restrict__ ebuf,
    const float* __restrict__ a_s, const float* __restrict__ a_d,
    const __hip_bfloat16* __restrict__ h,
    const void* __restrict__ bias, const void* __restrict__ gamma,
    const void* __restrict__ beta, void* __restrict__ out,
    const Flags* __restrict__ fl, int N)
{
    __shared__ int cnt[128], basel[128], cur[128];
    __shared__ int binned[BCAP];

    int fp32 = fl->fp32;
    int t = threadIdx.x;
    int b = blockIdx.x;

    if (t < 128) cnt[t] = 0;
    __syncthreads();

    // pass 1: count per-node
#pragma unroll
    for (int s = 0; s < 8; ++s) {
        int st = base8[s * 1024 + b];
        int c  = gcnt[s * 1024 + b];
        for (int i = t; i < c; i += 512) {
            unsigned int u = ebuf[st + i];
            atomicAdd(&cnt[(u >> 17) & 127], 1);
        }
    }
    __syncthreads();

    // scan cnt[128] by wave 0
    if (t < 64) {
        int a = cnt[2 * t], bb = cnt[2 * t + 1];
        int s2 = a + bb, val = s2;
#pragma unroll
        for (int off = 1; off < 64; off <<= 1) {
            int u = __shfl_up(val, off);
            if (t >= off) val += u;
        }
        int excl = val - s2;
        basel[2 * t] = excl;          cur[2 * t] = excl;
        basel[2 * t + 1] = excl + a;  cur[2 * t + 1] = excl + a;
    }
    __syncthreads();

    // pass 2: scatter srcs into per-node lists
#pragma unroll
    for (int s = 0; s < 8; ++s) {
        int st = base8[s * 1024 + b];
        int c  = gcnt[s * 1024 + b];
        for (int i = t; i < c; i += 512) {
            unsigned int u = ebuf[st + i];
            int pos = atomicAdd(&cur[(u >> 17) & 127], 1);
            if (pos < BCAP) binned[pos] = (int)(u & 0x1FFFF);
        }
    }
    __syncthreads();

    // node phase: 8 waves, 16 nodes each
    int wave = t >> 6, lane = t & 63;
    int hh = lane >> 3;
    int j0 = 2 * lane;
    const unsigned int* hw = (const unsigned int*)h;

    float bi0 = loadf(bias, j0, fp32),  bi1 = loadf(bias, j0 + 1, fp32);
    float ga0 = loadf(gamma, j0, fp32), ga1 = loadf(gamma, j0 + 1, fp32);
    float be0 = loadf(beta, j0, fp32),  be1 = loadf(beta, j0 + 1, fp32);

    for (int nl = wave; nl < 128; nl += 8) {
        int n = (b << BSH) + nl;
        if (n >= N) continue;

        float adv = a_d[n * HEADS + hh];
        float p = __expf(lrelu(a_s[n * HEADS + hh] + adv));
        float den = p;
        unsigned int hu = hw[((long long)n << 6) + lane];
        float acc0 = p * bflo(hu);
        float acc1 = p * bfhi(hu);

        int st  = __builtin_amdgcn_readfirstlane(basel[nl]);
        int dgl = __builtin_amdgcn_readfirstlane(min(cnt[nl], BCAP - st));

        for (int base = 0; base < dgl; base += 64) {
            int my = binned[st + min(base + lane, dgl - 1)];
            int m = min(64, dgl - base);
            int j = 0;
            for (; j + 4 <= m; j += 4) {
                int s0 = __builtin_amdgcn_readlane(my, j);
                int s1 = __builtin_amdgcn_readlane(my, j + 1);
                int s2 = __builtin_amdgcn_readlane(my, j + 2);
                int s3 = __builtin_amdgcn_readlane(my, j + 3);
                unsigned int u0 = hw[((long long)s0 << 6) + lane];
                unsigned int u1 = hw[((long long)s1 << 6) + lane];
                unsigned int u2 = hw[((long long)s2 << 6) + lane];
                unsigned int u3 = hw[((long long)s3 << 6) + lane];
                float as0 = a_s[s0 * HEADS + hh];
                float as1 = a_s[s1 * HEADS + hh];
                float as2 = a_s[s2 * HEADS + hh];
                float as3 = a_s[s3 * HEADS + hh];
                float p0 = __expf(lrelu(as0 + adv));
                float p1 = __expf(lrelu(as1 + adv));
                float p2 = __expf(lrelu(as2 + adv));
                float p3 = __expf(lrelu(as3 + adv));
                den += p0 + p1 + p2 + p3;
                acc0 = fmaf(p0, bflo(u0), acc0); acc1 = fmaf(p0, bfhi(u0), acc1);
                acc0 = fmaf(p1, bflo(u1), acc0); acc1 = fmaf(p1, bfhi(u1), acc1);
                acc0 = fmaf(p2, bflo(u2), acc0); acc1 = fmaf(p2, bfhi(u2), acc1);
                acc0 = fmaf(p3, bflo(u3), acc0); acc1 = fmaf(p3, bfhi(u3), acc1);
            }
            for (; j < m; ++j) {
                int s0 = __builtin_amdgcn_readlane(my, j);
                unsigned int u0 = hw[((long long)s0 << 6) + lane];
                float p0 = __expf(lrelu(a_s[s0 * HEADS + hh] + adv));
                den += p0;
                acc0 = fmaf(p0, bflo(u0), acc0);
                acc1 = fmaf(p0, bfhi(u0), acc1);
            }
        }

        float inv = 1.0f / den;
        float v0 = fin(acc0 * inv) + bi0;
        float v1 = fin(acc1 * inv) + bi1;

        float sum = v0 + v1;
#pragma unroll
        for (int off = 32; off; off >>= 1) sum += __shfl_xor(sum, off);
        float mu = sum * (1.0f / DIM);
        float d0 = v0 - mu, d1 = v1 - mu;
        float q = d0 * d0 + d1 * d1;
#pragma unroll
        for (int off = 32; off; off >>= 1) q += __shfl_xor(q, off);
        float rs = rsqrtf(q * (1.0f / DIM) + LN_EPS);

        float y0 = d0 * rs * ga0 + be0;
        float y1 = d1 * rs * ga1 + be1;
        y0 = y0 > 0.f ? y0 : expm1f(y0);
        y1 = y1 > 0.f ? y1 : expm1f(y1);

        long long oi = ((long long)n << 6) + lane;
        if (fp32) {
            ((float2*)out)[oi] = make_float2(y0, y1);
        } else {
            __hip_bfloat162 yv;
            yv.x = __float2bfloat16(y0);
            yv.y = __float2bfloat16(y1);
            ((__hip_bfloat162*)out)[oi] = yv;
        }
    }
}

extern "C" void kernel_launch(void* const* d_in, const int* in_sizes, int n_in,
                              void* d_out, int out_size, void* d_ws, size_t ws_size,
                              hipStream_t stream)
{
    const void* x    = d_in[0];
    const int*  ei   = (const int*)d_in[1];
    const void* W    = d_in[2];
    const void* atts = d_in[3];
    const void* attd = d_in[4];
    const void* bias = d_in[5];
    const void* gam  = d_in[6];
    const void* bet  = d_in[7];

    int N = in_sizes[0] / KD;   // 100000
    int E = in_sizes[1] / 2;    // 1600000
    int nb = (N + 127) >> BSH;  // 782 buckets

    // workspace layout (~33 MB)
    char* p = (char*)d_ws;
    Flags* fl      = (Flags*)p; p += 1024;
    float* a_s     = (float*)p; p += (size_t)N * HEADS * sizeof(float);
    float* a_d     = (float*)p; p += (size_t)N * HEADS * sizeof(float);
    __hip_bfloat16* h = (__hip_bfloat16*)p; p += (size_t)N * DIM * sizeof(__hip_bfloat16);
    int* gcnt      = (int*)p;   p += 8 * 1024 * sizeof(int);
    int* base8     = (int*)p;   p += 8 * 1024 * sizeof(int);
    int* gcur      = (int*)p;   p += 8 * 1024 * sizeof(int);
    unsigned int* ebuf = (unsigned int*)p; p += (size_t)E * sizeof(unsigned int);

    k_detect<<<1, 64, 0, stream>>>((const unsigned int*)x, ei, fl);
    hipMemsetAsync(gcnt, 0, 8 * 1024 * sizeof(int), stream);

    k_gemm_lds<<<(N + GN - 1) / GN, 256, 0, stream>>>(x, W, atts, attd, h, a_s, a_d, fl, N);

    k_bhist<<<256, 256, 0, stream>>>(ei, gcnt, fl, E, N);
    k_bscan<<<1, 1024, 0, stream>>>(gcnt, base8, gcur);
    k_bscatter<<<(E + 255) / 256, 256, 0, stream>>>(ei, gcur, ebuf, fl, E, N);

    k_fused_b<<<nb, 512, 0, stream>>>(gcnt, base8, ebuf, a_s, a_d, h,
                                      bias, gam, bet, d_out, fl, N);
}